// Round 3
// baseline (382.816 us; speedup 1.0000x reference)
//
#include <hip/hip_runtime.h>
#include <math.h>

#define B_ 4
#define T_ 2048
#define C_ 1024
#define H_ 16
#define D_ 64
#define M_ (B_*T_)      // 8192
#define N1_ (3*C_)      // 3072

typedef __attribute__((ext_vector_type(8))) short bf16x8;
typedef __attribute__((ext_vector_type(4))) short bf16x4;
typedef __attribute__((ext_vector_type(4))) float f32x4;
typedef __attribute__((ext_vector_type(16))) float f32x16;

__device__ __forceinline__ short f2bf(float f){
  union { float f; unsigned u; } v; v.f = f;
  unsigned r = (v.u + 0x7fffu + ((v.u >> 16) & 1u)) >> 16;
  return (short)r;
}

__device__ __forceinline__ unsigned cvtpk(float lo, float hi){
  unsigned r;
  asm("v_cvt_pk_bf16_f32 %0, %1, %2" : "=v"(r) : "v"(lo), "v"(hi));
  return r;
}

__device__ __forceinline__ void gll16(const void* g, void* l){
  __builtin_amdgcn_global_load_lds((const __attribute__((address_space(1))) void*)g,
                                   (__attribute__((address_space(3))) void*)l, 16, 0, 0);
}

// ---- convert x (f32) -> bf16 ----
__global__ __launch_bounds__(256) void convx(const float* __restrict__ x, short* __restrict__ xb, int n){
  int i = (blockIdx.x*256 + threadIdx.x)*8;
  if (i >= n) return;
  float4 a = *(const float4*)(x+i), b = *(const float4*)(x+i+4);
  bf16x8 o;
  o[0]=f2bf(a.x); o[1]=f2bf(a.y); o[2]=f2bf(a.z); o[3]=f2bf(a.w);
  o[4]=f2bf(b.x); o[5]=f2bf(b.y); o[6]=f2bf(b.z); o[7]=f2bf(b.w);
  *(bf16x8*)(xb+i) = o;
}

// ---- transpose W (K,N) f32 -> Wt (N,K) bf16 ----
__global__ __launch_bounds__(256) void transw(const float* __restrict__ W, short* __restrict__ Wt, int K, int N){
  __shared__ float tl[64][72];
  int tid = threadIdx.x;
  int n0 = blockIdx.x*64, k0 = blockIdx.y*64;
  #pragma unroll
  for (int i=0;i<4;i++){
    int row = (tid>>4) + i*16;
    int col4 = (tid&15)*4;
    float4 v = *(const float4*)&W[(size_t)(k0+row)*N + n0 + col4];
    *(float4*)&tl[row][col4] = v;
  }
  __syncthreads();
  #pragma unroll
  for (int i=0;i<2;i++){
    int nr = (tid>>3) + i*32;
    int ch = tid&7;
    bf16x8 o;
    #pragma unroll
    for (int e=0;e<8;e++) o[e] = f2bf(tl[ch*8+e][nr]);
    *(bf16x8*)&Wt[(size_t)(n0+nr)*K + k0 + ch*8] = o;
  }
}

// ---- GEMM: out(M,N) = A(M,K) @ Bt(N,K)^T + bias.  128x128 tile, 4 waves ----
template<int OUTBF>
__global__ __launch_bounds__(256) void gemm_bt(const short* __restrict__ A, const short* __restrict__ Bt,
           const float* __restrict__ bias, short* __restrict__ outb, float* __restrict__ outf,
           int M, int N, int K)
{
  __shared__ short As[128*32];
  __shared__ short Bs[128*32];
  const int tid = threadIdx.x;
  const int wv = tid >> 6, ln = tid & 63;
  const int lnr = ln & 15, lg = ln >> 4;
  const int m0 = blockIdx.y * 128, n0 = blockIdx.x * 128;
  const int wm = wv >> 1, wn = wv & 1;
  f32x4 acc[4][4];
  #pragma unroll
  for(int i=0;i<4;i++)
    #pragma unroll
    for(int j=0;j<4;j++) acc[i][j] = (f32x4){0.f,0.f,0.f,0.f};

  for (int k0 = 0; k0 < K; k0 += 32){
    #pragma unroll
    for (int c = 0; c < 2; c++){
      int i = c*256 + tid;
      gll16(A  + (size_t)(m0 + (i>>2))*K + k0 + (i&3)*8, (void*)(As + (c*256 + wv*64)*8));
      gll16(Bt + (size_t)(n0 + (i>>2))*K + k0 + (i&3)*8, (void*)(Bs + (c*256 + wv*64)*8));
    }
    __syncthreads();
    bf16x8 af[4], bfr[4];
    #pragma unroll
    for (int mi=0;mi<4;mi++) af[mi]  = *(const bf16x8*)&As[(wm*64 + mi*16 + lnr)*32 + lg*8];
    #pragma unroll
    for (int ni=0;ni<4;ni++) bfr[ni] = *(const bf16x8*)&Bs[(wn*64 + ni*16 + lnr)*32 + lg*8];
    #pragma unroll
    for (int mi=0;mi<4;mi++)
      #pragma unroll
      for (int ni=0;ni<4;ni++)
        acc[mi][ni] = __builtin_amdgcn_mfma_f32_16x16x32_bf16(af[mi], bfr[ni], acc[mi][ni], 0,0,0);
    __syncthreads();
  }

  #pragma unroll
  for (int mi=0;mi<4;mi++){
    #pragma unroll
    for (int ni=0;ni<4;ni++){
      int col = n0 + wn*64 + ni*16 + lnr;
      float bv = bias[col];
      #pragma unroll
      for (int r=0;r<4;r++){
        int row = m0 + wm*64 + mi*16 + lg*4 + r;
        float v = acc[mi][ni][r] + bv;
        if (OUTBF) outb[(size_t)row*N + col] = f2bf(v);
        else       outf[(size_t)row*N + col] = v;
      }
    }
  }
}

// ---- transpose V slice of qkv -> vt (B*H, D, T) bf16 ----
__global__ __launch_bounds__(256) void transv(const short* __restrict__ qkv, short* __restrict__ vt){
  __shared__ short tl[64][72];
  int tid = threadIdx.x;
  int t0 = blockIdx.x*64, bh = blockIdx.y;
  int b = bh>>4, h = bh&15;
  int tr = tid>>2, cc = (tid&3)*16;
  const short* src = &qkv[(size_t)(b*T_ + t0 + tr)*N1_ + 2*C_ + h*D_ + cc];
  #pragma unroll
  for (int i=0;i<4;i++){
    bf16x4 v = *(const bf16x4*)(src + i*4);
    *(bf16x4*)&tl[tr][cc + i*4] = v;
  }
  __syncthreads();
  int d = tid>>2, tc = (tid&3)*16;
  #pragma unroll
  for (int i=0;i<2;i++){
    bf16x8 o;
    #pragma unroll
    for (int e=0;e<8;e++) o[e] = tl[tc + i*8 + e][d];
    *(bf16x8*)&vt[(size_t)(bh*D_ + d)*T_ + t0 + tc + i*8] = o;
  }
}

// ---- flash attention v3: K-split across 2 waves/block + LDS merge ----
// Block = 128 threads = 2 waves. Wave h handles tile range of one 32-row q-strip.
__global__ __launch_bounds__(128, 4) void attn3(const short* __restrict__ qkv, const short* __restrict__ vt,
           const int* __restrict__ mask, short* __restrict__ yb)
{
  __shared__ float lo[32][64];     // partial O from wave 1 (8 KB)
  __shared__ float lm[32], ll[32];
  const int tid = threadIdx.x;
  const int h = tid>>6, ln = tid&63;
  const int l31 = ln & 31, hi = ln >> 5;
  const int bh = blockIdx.y, b = bh>>4, hd = bh&15;
  const int s = 63 - (int)blockIdx.x;    // heavy strips dispatch first (LPT)
  const int q0w = s*32;
  const int nt = (s>>1) + 1;
  const int nh0 = nt - (nt>>1);
  const int jbeg = h ? nh0 : 0;
  const int jend = h ? nt : nh0;
  const float cexp = 0.18033688f;        // 0.125 * log2(e)

  // Q fragments (B-operand): lane holds Q[q0w + l31][ds*16 + hi*8 + e]
  bf16x8 qf[4];
  const short* qbase = qkv + (size_t)(b*T_ + q0w + l31)*N1_ + hd*D_ + hi*8;
  #pragma unroll
  for (int ds=0; ds<4; ds++) qf[ds] = *(const bf16x8*)(qbase + ds*16);

  f32x16 o0, o1;
  #pragma unroll
  for (int r=0;r<16;r++){ o0[r]=0.f; o1[r]=0.f; }
  float mrow = -INFINITY, lsum = 0.f;

  for (int jt = jbeg; jt < jend; jt++){
    const int j0 = jt << 6;
    int mval = mask[b*T_ + j0 + ln];
    unsigned long long bm = __ballot(mval != 0);

    // K fragments (A-operand) + QK^T (swapped): s = S^T
    const short* kbase = qkv + (size_t)(b*T_ + j0 + l31)*N1_ + C_ + hd*D_ + hi*8;
    f32x16 s0, s1;
    #pragma unroll
    for (int r=0;r<16;r++){ s0[r]=0.f; s1[r]=0.f; }
    #pragma unroll
    for (int ds=0; ds<4; ds++){
      bf16x8 k0 = *(const bf16x8*)(kbase + ds*16);
      bf16x8 k1 = *(const bf16x8*)(kbase + (size_t)32*N1_ + ds*16);
      s0 = __builtin_amdgcn_mfma_f32_32x32x16_bf16(k0, qf[ds], s0, 0,0,0);
      s1 = __builtin_amdgcn_mfma_f32_32x32x16_bf16(k1, qf[ds], s1, 0,0,0);
    }

    // masking in raw-s domain
    const int qglob = q0w + l31;
    const bool allm = (bm == ~0ull);
    if (!allm){
      #pragma unroll
      for (int r=0;r<16;r++){
        int kr = (r&3) + 8*(r>>2) + 4*hi;
        bool ok0 = (j0 + kr      <= qglob) && ((bm >> kr) & 1);
        bool ok1 = (j0 + kr + 32 <= qglob) && ((bm >> (kr+32)) & 1);
        s0[r] = ok0 ? s0[r] : -INFINITY;
        s1[r] = ok1 ? s1[r] : -INFINITY;
      }
    } else if (j0 + 63 > q0w){   // diagonal tile: causal only
      #pragma unroll
      for (int r=0;r<16;r++){
        int kr = (r&3) + 8*(r>>2) + 4*hi;
        s0[r] = (j0 + kr      <= qglob) ? s0[r] : -INFINITY;
        s1[r] = (j0 + kr + 32 <= qglob) ? s1[r] : -INFINITY;
      }
    }

    // tile max (register tree + one cross-half swap)
    float t[8];
    #pragma unroll
    for (int i=0;i<8;i++) t[i] = fmaxf(fmaxf(s0[i], s0[i+8]), fmaxf(s1[i], s1[i+8]));
    #pragma unroll
    for (int i=0;i<4;i++) t[i] = fmaxf(t[i], t[i+4]);
    float pm = fmaxf(fmaxf(t[0],t[1]), fmaxf(t[2],t[3]));
    pm = fmaxf(pm, __shfl_xor(pm, 32));

    // defer-max
    if (!__all(pm - mrow <= 40.0f)){
      float nm = fmaxf(mrow, pm);
      float alpha = __builtin_amdgcn_exp2f((mrow - nm)*cexp);
      lsum *= alpha;
      mrow = nm;
      #pragma unroll
      for (int r=0;r<16;r++){
        int qsrc = (r&3) + 8*(r>>2) + 4*hi;
        float aO = __shfl(alpha, qsrc);
        o0[r] *= aO; o1[r] *= aO;
      }
    }

    // p = exp2((s-m)*c), in place (saves 32 VGPRs)
    #pragma unroll
    for (int r=0;r<16;r++){
      s0[r] = __builtin_amdgcn_exp2f((s0[r]-mrow)*cexp);
      s1[r] = __builtin_amdgcn_exp2f((s1[r]-mrow)*cexp);
    }
    // tile sum
    float u[8];
    #pragma unroll
    for (int i=0;i<8;i++) u[i] = (s0[i]+s0[i+8]) + (s1[i]+s1[i+8]);
    #pragma unroll
    for (int i=0;i<4;i++) u[i] = u[i] + u[i+4];
    float ps = (u[0]+u[1]) + (u[2]+u[3]);
    ps += __shfl_xor(ps, 32);
    lsum += ps;

    // V fragments (hoisted: VMEM latency hides under pack)
    const short* vbase = vt + (size_t)(bh*D_ + l31)*T_ + j0 + hi*8;
    bf16x8 vf0[4], vf1[4];
    #pragma unroll
    for (int kt2=0; kt2<4; kt2++){
      vf0[kt2] = *(const bf16x8*)(vbase + kt2*16);
      vf1[kt2] = *(const bf16x8*)(vbase + (size_t)32*T_ + kt2*16);
    }

    // pack P -> bf16 A-fragments: cvt_pk + cross-half swap (no LDS)
    unsigned LA[2][4], LB[2][4], SA[2][4], SB[2][4];
    #pragma unroll
    for (int rq=0; rq<4; rq++){
      LA[0][rq] = cvtpk(s0[4*rq],   s0[4*rq+1]);
      LB[0][rq] = cvtpk(s0[4*rq+2], s0[4*rq+3]);
      LA[1][rq] = cvtpk(s1[4*rq],   s1[4*rq+1]);
      LB[1][rq] = cvtpk(s1[4*rq+2], s1[4*rq+3]);
    }
    #pragma unroll
    for (int kt=0; kt<2; kt++)
      #pragma unroll
      for (int rq=0; rq<4; rq++){
        SA[kt][rq] = (unsigned)__shfl_xor((int)LA[kt][rq], 32);
        SB[kt][rq] = (unsigned)__shfl_xor((int)LB[kt][rq], 32);
      }

    // PV
    #pragma unroll
    for (int kt2=0; kt2<4; kt2++){
      const int kt = kt2>>1, sub = kt2&1;
      union { unsigned u[4]; bf16x8 v; } pf;
      pf.u[0] = hi ? SA[kt][2*sub+1] : LA[kt][2*sub];
      pf.u[1] = hi ? SB[kt][2*sub+1] : LB[kt][2*sub];
      pf.u[2] = hi ? LA[kt][2*sub+1] : SA[kt][2*sub];
      pf.u[3] = hi ? LB[kt][2*sub+1] : SB[kt][2*sub];
      o0 = __builtin_amdgcn_mfma_f32_32x32x16_bf16(pf.v, vf0[kt2], o0, 0,0,0);
      o1 = __builtin_amdgcn_mfma_f32_32x32x16_bf16(pf.v, vf1[kt2], o1, 0,0,0);
    }
  }

  // ---- merge the two K-halves via LDS ----
  if (h == 1){
    #pragma unroll
    for (int r=0;r<16;r++){
      int qs = (r&3) + 8*(r>>2) + 4*hi;
      lo[qs][l31]      = o0[r];
      lo[qs][l31 + 32] = o1[r];
    }
    if (hi == 0){ lm[l31] = mrow; ll[l31] = lsum; }
  }
  __syncthreads();
  if (h == 0){
    float mB = lm[l31], lB = ll[l31];
    float mst = fmaxf(mrow, mB);
    float aA = __builtin_amdgcn_exp2f((mrow - mst)*cexp);
    float aB = (lB > 0.f) ? __builtin_amdgcn_exp2f((mB - mst)*cexp) : 0.f;
    float lst = lsum*aA + lB*aB;
    float fA = aA/lst, fB = aB/lst;
    #pragma unroll
    for (int r=0;r<16;r++){
      int qs = (r&3) + 8*(r>>2) + 4*hi;
      float gA = __shfl(fA, qs), gB = __shfl(fB, qs);
      float v0 = o0[r]*gA + lo[qs][l31]*gB;
      float v1 = o1[r]*gA + lo[qs][l31+32]*gB;
      size_t base = (size_t)(b*T_ + q0w + qs)*C_ + hd*D_ + l31;
      yb[base]      = f2bf(v0);
      yb[base + 32] = f2bf(v1);
    }
  }
}

extern "C" void kernel_launch(void* const* d_in, const int* in_sizes, int n_in,
                              void* d_out, int out_size, void* d_ws, size_t ws_size,
                              hipStream_t stream){
  const float* x     = (const float*)d_in[0];
  const int*   mask  = (const int*)d_in[1];
  const float* Wqkv  = (const float*)d_in[2];
  const float* bqkv  = (const float*)d_in[3];
  const float* Wproj = (const float*)d_in[4];
  const float* bproj = (const float*)d_in[5];
  float* out = (float*)d_out;

  char* w = (char*)d_ws;
  short* xb     = (short*)w; w += (size_t)M_*C_*2;
  short* wqkvT  = (short*)w; w += (size_t)N1_*C_*2;
  short* wprojT = (short*)w; w += (size_t)C_*C_*2;
  short* qkvb   = (short*)w; w += (size_t)M_*N1_*2;
  short* vtb    = (short*)w; w += (size_t)B_*H_*D_*T_*2;
  short* yb     = (short*)w; w += (size_t)M_*C_*2;

  convx<<<dim3((M_*C_)/(256*8)), 256, 0, stream>>>(x, xb, M_*C_);
  transw<<<dim3(N1_/64, C_/64), 256, 0, stream>>>(Wqkv, wqkvT, C_, N1_);
  transw<<<dim3(C_/64,  C_/64), 256, 0, stream>>>(Wproj, wprojT, C_, C_);
  gemm_bt<1><<<dim3(N1_/128, M_/128), 256, 0, stream>>>(xb, wqkvT, bqkv, qkvb, nullptr, M_, N1_, C_);
  transv<<<dim3(T_/64, B_*H_), 256, 0, stream>>>(qkvb, vtb);
  attn3<<<dim3(64, B_*H_), 128, 0, stream>>>(qkvb, vtb, mask, yb);
  gemm_bt<0><<<dim3(C_/128, M_/128), 256, 0, stream>>>(yb, wprojT, bproj, nullptr, out, M_, C_, C_);
}

// Round 4
// 307.162 us; speedup vs baseline: 1.2463x; 1.2463x over previous
//
#include <hip/hip_runtime.h>
#include <math.h>

#define B_ 4
#define T_ 2048
#define C_ 1024
#define H_ 16
#define D_ 64
#define M_ (B_*T_)      // 8192
#define N1_ (3*C_)      // 3072

typedef __attribute__((ext_vector_type(8))) short bf16x8;
typedef __attribute__((ext_vector_type(4))) short bf16x4;
typedef __attribute__((ext_vector_type(4))) float f32x4;
typedef __attribute__((ext_vector_type(16))) float f32x16;

__device__ __forceinline__ short f2bf(float f){
  union { float f; unsigned u; } v; v.f = f;
  unsigned r = (v.u + 0x7fffu + ((v.u >> 16) & 1u)) >> 16;
  return (short)r;
}

__device__ __forceinline__ unsigned cvtpk(float lo, float hi){
  unsigned r;
  asm("v_cvt_pk_bf16_f32 %0, %1, %2" : "=v"(r) : "v"(lo), "v"(hi));
  return r;
}

__device__ __forceinline__ void gll16(const void* g, void* l){
  __builtin_amdgcn_global_load_lds((const __attribute__((address_space(1))) void*)g,
                                   (__attribute__((address_space(3))) void*)l, 16, 0, 0);
}

// ---- convert x (f32) -> bf16 ----
__global__ __launch_bounds__(256) void convx(const float* __restrict__ x, short* __restrict__ xb, int n){
  int i = (blockIdx.x*256 + threadIdx.x)*8;
  if (i >= n) return;
  float4 a = *(const float4*)(x+i), b = *(const float4*)(x+i+4);
  bf16x8 o;
  o[0]=f2bf(a.x); o[1]=f2bf(a.y); o[2]=f2bf(a.z); o[3]=f2bf(a.w);
  o[4]=f2bf(b.x); o[5]=f2bf(b.y); o[6]=f2bf(b.z); o[7]=f2bf(b.w);
  *(bf16x8*)(xb+i) = o;
}

// ---- transpose W (K,N) f32 -> Wt (N,K) bf16 ----
__global__ __launch_bounds__(256) void transw(const float* __restrict__ W, short* __restrict__ Wt, int K, int N){
  __shared__ float tl[64][72];
  int tid = threadIdx.x;
  int n0 = blockIdx.x*64, k0 = blockIdx.y*64;
  #pragma unroll
  for (int i=0;i<4;i++){
    int row = (tid>>4) + i*16;
    int col4 = (tid&15)*4;
    float4 v = *(const float4*)&W[(size_t)(k0+row)*N + n0 + col4];
    *(float4*)&tl[row][col4] = v;
  }
  __syncthreads();
  #pragma unroll
  for (int i=0;i<2;i++){
    int nr = (tid>>3) + i*32;
    int ch = tid&7;
    bf16x8 o;
    #pragma unroll
    for (int e=0;e<8;e++) o[e] = f2bf(tl[ch*8+e][nr]);
    *(bf16x8*)&Wt[(size_t)(n0+nr)*K + k0 + ch*8] = o;
  }
}

// ---- GEMM: out(M,N) = A(M,K) @ Bt(N,K)^T + bias.  128x128 tile, 4 waves ----
template<int OUTBF>
__global__ __launch_bounds__(256) void gemm_bt(const short* __restrict__ A, const short* __restrict__ Bt,
           const float* __restrict__ bias, short* __restrict__ outb, float* __restrict__ outf,
           int M, int N, int K)
{
  __shared__ short As[128*32];
  __shared__ short Bs[128*32];
  const int tid = threadIdx.x;
  const int wv = tid >> 6, ln = tid & 63;
  const int lnr = ln & 15, lg = ln >> 4;
  const int m0 = blockIdx.y * 128, n0 = blockIdx.x * 128;
  const int wm = wv >> 1, wn = wv & 1;
  f32x4 acc[4][4];
  #pragma unroll
  for(int i=0;i<4;i++)
    #pragma unroll
    for(int j=0;j<4;j++) acc[i][j] = (f32x4){0.f,0.f,0.f,0.f};

  for (int k0 = 0; k0 < K; k0 += 32){
    #pragma unroll
    for (int c = 0; c < 2; c++){
      int i = c*256 + tid;
      gll16(A  + (size_t)(m0 + (i>>2))*K + k0 + (i&3)*8, (void*)(As + (c*256 + wv*64)*8));
      gll16(Bt + (size_t)(n0 + (i>>2))*K + k0 + (i&3)*8, (void*)(Bs + (c*256 + wv*64)*8));
    }
    __syncthreads();
    bf16x8 af[4], bfr[4];
    #pragma unroll
    for (int mi=0;mi<4;mi++) af[mi]  = *(const bf16x8*)&As[(wm*64 + mi*16 + lnr)*32 + lg*8];
    #pragma unroll
    for (int ni=0;ni<4;ni++) bfr[ni] = *(const bf16x8*)&Bs[(wn*64 + ni*16 + lnr)*32 + lg*8];
    #pragma unroll
    for (int mi=0;mi<4;mi++)
      #pragma unroll
      for (int ni=0;ni<4;ni++)
        acc[mi][ni] = __builtin_amdgcn_mfma_f32_16x16x32_bf16(af[mi], bfr[ni], acc[mi][ni], 0,0,0);
    __syncthreads();
  }

  #pragma unroll
  for (int mi=0;mi<4;mi++){
    #pragma unroll
    for (int ni=0;ni<4;ni++){
      int col = n0 + wn*64 + ni*16 + lnr;
      float bv = bias[col];
      #pragma unroll
      for (int r=0;r<4;r++){
        int row = m0 + wm*64 + mi*16 + lg*4 + r;
        float v = acc[mi][ni][r] + bv;
        if (OUTBF) outb[(size_t)row*N + col] = f2bf(v);
        else       outf[(size_t)row*N + col] = v;
      }
    }
  }
}

// ---- transpose V slice of qkv -> vt (B*H, D, T) bf16 ----
__global__ __launch_bounds__(256) void transv(const short* __restrict__ qkv, short* __restrict__ vt){
  __shared__ short tl[64][72];
  int tid = threadIdx.x;
  int t0 = blockIdx.x*64, bh = blockIdx.y;
  int b = bh>>4, h = bh&15;
  int tr = tid>>2, cc = (tid&3)*16;
  const short* src = &qkv[(size_t)(b*T_ + t0 + tr)*N1_ + 2*C_ + h*D_ + cc];
  #pragma unroll
  for (int i=0;i<4;i++){
    bf16x4 v = *(const bf16x4*)(src + i*4);
    *(bf16x4*)&tl[tr][cc + i*4] = v;
  }
  __syncthreads();
  int d = tid>>2, tc = (tid&3)*16;
  #pragma unroll
  for (int i=0;i<2;i++){
    bf16x8 o;
    #pragma unroll
    for (int e=0;e<8;e++) o[e] = tl[tc + i*8 + e][d];
    *(bf16x8*)&vt[(size_t)(bh*D_ + d)*T_ + t0 + tc + i*8] = o;
  }
}

// ---- flash attention v4: 1 wave/block, 4096 blocks, register-lean, LPT + XCD-local ----
__global__ __launch_bounds__(64) void attn4(const short* __restrict__ qkv, const short* __restrict__ vt,
           const int* __restrict__ mask, short* __restrict__ yb)
{
  const int ln = threadIdx.x & 63;
  const int l31 = ln & 31, hi = ln >> 5;
  const int bh = blockIdx.x, b = bh>>4, hd = bh&15;
  const int s = 63 - (int)blockIdx.y;    // heavy strips dispatch first (LPT)
  const int q0w = s*32;
  const int nt = (s>>1) + 1;
  const float cexp = 0.18033688f;        // 0.125 * log2(e)

  // Q fragments (B-operand): lane holds Q[q0w + l31][ds*16 + hi*8 + e]
  bf16x8 qf[4];
  const short* qbase = qkv + (size_t)(b*T_ + q0w + l31)*N1_ + hd*D_ + hi*8;
  #pragma unroll
  for (int ds=0; ds<4; ds++) qf[ds] = *(const bf16x8*)(qbase + ds*16);

  f32x16 o0, o1;
  #pragma unroll
  for (int r=0;r<16;r++){ o0[r]=0.f; o1[r]=0.f; }
  float mrow = -INFINITY, lsum = 0.f;

  for (int jt = 0; jt < nt; jt++){
    const int j0 = jt << 6;
    int mval = mask[b*T_ + j0 + ln];
    unsigned long long bm = __ballot(mval != 0);

    // K fragments (A-operand) + QK^T (swapped): s = S^T
    const short* kbase = qkv + (size_t)(b*T_ + j0 + l31)*N1_ + C_ + hd*D_ + hi*8;
    f32x16 s0, s1;
    #pragma unroll
    for (int r=0;r<16;r++){ s0[r]=0.f; s1[r]=0.f; }
    __builtin_amdgcn_s_setprio(1);
    #pragma unroll
    for (int ds=0; ds<4; ds++){
      bf16x8 k0 = *(const bf16x8*)(kbase + ds*16);
      bf16x8 k1 = *(const bf16x8*)(kbase + (size_t)32*N1_ + ds*16);
      s0 = __builtin_amdgcn_mfma_f32_32x32x16_bf16(k0, qf[ds], s0, 0,0,0);
      s1 = __builtin_amdgcn_mfma_f32_32x32x16_bf16(k1, qf[ds], s1, 0,0,0);
    }
    __builtin_amdgcn_s_setprio(0);

    // masking in raw-s domain
    const int qglob = q0w + l31;
    const bool allm = (bm == ~0ull);
    if (!allm){
      #pragma unroll
      for (int r=0;r<16;r++){
        int kr = (r&3) + 8*(r>>2) + 4*hi;
        bool ok0 = (j0 + kr      <= qglob) && ((bm >> kr) & 1);
        bool ok1 = (j0 + kr + 32 <= qglob) && ((bm >> (kr+32)) & 1);
        s0[r] = ok0 ? s0[r] : -INFINITY;
        s1[r] = ok1 ? s1[r] : -INFINITY;
      }
    } else if (j0 + 63 > q0w){   // diagonal tile: causal only
      #pragma unroll
      for (int r=0;r<16;r++){
        int kr = (r&3) + 8*(r>>2) + 4*hi;
        s0[r] = (j0 + kr      <= qglob) ? s0[r] : -INFINITY;
        s1[r] = (j0 + kr + 32 <= qglob) ? s1[r] : -INFINITY;
      }
    }

    // tile max (register tree + one cross-half swap)
    float t[8];
    #pragma unroll
    for (int i=0;i<8;i++) t[i] = fmaxf(fmaxf(s0[i], s0[i+8]), fmaxf(s1[i], s1[i+8]));
    #pragma unroll
    for (int i=0;i<4;i++) t[i] = fmaxf(t[i], t[i+4]);
    float pm = fmaxf(fmaxf(t[0],t[1]), fmaxf(t[2],t[3]));
    pm = fmaxf(pm, __shfl_xor(pm, 32));

    // defer-max: rescale only when max grew past threshold
    if (!__all(pm - mrow <= 40.0f)){
      float nm = fmaxf(mrow, pm);
      float alpha = __builtin_amdgcn_exp2f((mrow - nm)*cexp);
      lsum *= alpha;
      mrow = nm;
      #pragma unroll
      for (int r=0;r<16;r++){
        int qsrc = (r&3) + 8*(r>>2) + 4*hi;
        float aO = __shfl(alpha, qsrc);
        o0[r] *= aO; o1[r] *= aO;
      }
    }

    // p = exp2((s-m)*c), in place
    #pragma unroll
    for (int r=0;r<16;r++){
      s0[r] = __builtin_amdgcn_exp2f((s0[r]-mrow)*cexp);
      s1[r] = __builtin_amdgcn_exp2f((s1[r]-mrow)*cexp);
    }
    // tile sum
    float u[8];
    #pragma unroll
    for (int i=0;i<8;i++) u[i] = (s0[i]+s0[i+8]) + (s1[i]+s1[i+8]);
    #pragma unroll
    for (int i=0;i<4;i++) u[i] = u[i] + u[i+4];
    float ps = (u[0]+u[1]) + (u[2]+u[3]);
    ps += __shfl_xor(ps, 32);
    lsum += ps;

    // PV: per-kt2 inline pack (cvt_pk + cross-half swap) + V load + MFMA.
    // Short transient live ranges keep VGPR pressure down.
    const short* vbase = vt + (size_t)(bh*D_ + l31)*T_ + j0 + hi*8;
    #pragma unroll
    for (int kt2=0; kt2<4; kt2++){
      const int sub = kt2 & 1;
      bf16x8 vf0 = *(const bf16x8*)(vbase + kt2*16);
      bf16x8 vf1 = *(const bf16x8*)(vbase + (size_t)32*T_ + kt2*16);
      unsigned A0, B0, A1, B1;
      if (kt2 < 2){
        A0 = cvtpk(s0[8*sub+0], s0[8*sub+1]);
        B0 = cvtpk(s0[8*sub+2], s0[8*sub+3]);
        A1 = cvtpk(s0[8*sub+4], s0[8*sub+5]);
        B1 = cvtpk(s0[8*sub+6], s0[8*sub+7]);
      } else {
        A0 = cvtpk(s1[8*sub+0], s1[8*sub+1]);
        B0 = cvtpk(s1[8*sub+2], s1[8*sub+3]);
        A1 = cvtpk(s1[8*sub+4], s1[8*sub+5]);
        B1 = cvtpk(s1[8*sub+6], s1[8*sub+7]);
      }
      unsigned sA0 = (unsigned)__shfl_xor((int)A0, 32);
      unsigned sA1 = (unsigned)__shfl_xor((int)A1, 32);
      unsigned sB0 = (unsigned)__shfl_xor((int)B0, 32);
      unsigned sB1 = (unsigned)__shfl_xor((int)B1, 32);
      union { unsigned u[4]; bf16x8 v; } pf;
      pf.u[0] = hi ? sA1 : A0;
      pf.u[1] = hi ? sB1 : B0;
      pf.u[2] = hi ? A1 : sA0;
      pf.u[3] = hi ? B1 : sB0;
      __builtin_amdgcn_s_setprio(1);
      o0 = __builtin_amdgcn_mfma_f32_32x32x16_bf16(pf.v, vf0, o0, 0,0,0);
      o1 = __builtin_amdgcn_mfma_f32_32x32x16_bf16(pf.v, vf1, o1, 0,0,0);
      __builtin_amdgcn_s_setprio(0);
    }
  }

  // epilogue: normalize + store bf16
  float linv = 1.0f / lsum;
  #pragma unroll
  for (int r=0;r<16;r++){
    int qs = (r&3) + 8*(r>>2) + 4*hi;
    float lv = __shfl(linv, qs);
    size_t base = (size_t)(b*T_ + q0w + qs)*C_ + hd*D_ + l31;
    yb[base]      = f2bf(o0[r]*lv);
    yb[base + 32] = f2bf(o1[r]*lv);
  }
}

extern "C" void kernel_launch(void* const* d_in, const int* in_sizes, int n_in,
                              void* d_out, int out_size, void* d_ws, size_t ws_size,
                              hipStream_t stream){
  const float* x     = (const float*)d_in[0];
  const int*   mask  = (const int*)d_in[1];
  const float* Wqkv  = (const float*)d_in[2];
  const float* bqkv  = (const float*)d_in[3];
  const float* Wproj = (const float*)d_in[4];
  const float* bproj = (const float*)d_in[5];
  float* out = (float*)d_out;

  char* w = (char*)d_ws;
  short* xb     = (short*)w; w += (size_t)M_*C_*2;
  short* wqkvT  = (short*)w; w += (size_t)N1_*C_*2;
  short* wprojT = (short*)w; w += (size_t)C_*C_*2;
  short* qkvb   = (short*)w; w += (size_t)M_*N1_*2;
  short* vtb    = (short*)w; w += (size_t)B_*H_*D_*T_*2;
  short* yb     = (short*)w; w += (size_t)M_*C_*2;

  convx<<<dim3((M_*C_)/(256*8)), 256, 0, stream>>>(x, xb, M_*C_);
  transw<<<dim3(N1_/64, C_/64), 256, 0, stream>>>(Wqkv, wqkvT, C_, N1_);
  transw<<<dim3(C_/64,  C_/64), 256, 0, stream>>>(Wproj, wprojT, C_, C_);
  gemm_bt<1><<<dim3(N1_/128, M_/128), 256, 0, stream>>>(xb, wqkvT, bqkv, qkvb, nullptr, M_, N1_, C_);
  transv<<<dim3(T_/64, B_*H_), 256, 0, stream>>>(qkvb, vtb);
  attn4<<<dim3(B_*H_, 64), 64, 0, stream>>>(qkvb, vtb, mask, yb);
  gemm_bt<0><<<dim3(C_/128, M_/128), 256, 0, stream>>>(yb, wprojT, bproj, nullptr, out, M_, C_, C_);
}

// Round 5
// 254.121 us; speedup vs baseline: 1.5064x; 1.2087x over previous
//
#include <hip/hip_runtime.h>
#include <math.h>

#define B_ 4
#define T_ 2048
#define C_ 1024
#define H_ 16
#define D_ 64
#define M_ (B_*T_)      // 8192
#define N1_ (3*C_)      // 3072

typedef __attribute__((ext_vector_type(8))) short bf16x8;
typedef __attribute__((ext_vector_type(4))) short bf16x4;
typedef __attribute__((ext_vector_type(4))) float f32x4;
typedef __attribute__((ext_vector_type(16))) float f32x16;

__device__ __forceinline__ short f2bf(float f){
  union { float f; unsigned u; } v; v.f = f;
  unsigned r = (v.u + 0x7fffu + ((v.u >> 16) & 1u)) >> 16;
  return (short)r;
}

__device__ __forceinline__ unsigned cvtpk(float lo, float hi){
  unsigned r;
  asm("v_cvt_pk_bf16_f32 %0, %1, %2" : "=v"(r) : "v"(lo), "v"(hi));
  return r;
}

__device__ __forceinline__ void gll16(const void* g, void* l){
  __builtin_amdgcn_global_load_lds((const __attribute__((address_space(1))) void*)g,
                                   (__attribute__((address_space(3))) void*)l, 16, 0, 0);
}

// ---- convert x (f32) -> bf16 ----
__global__ __launch_bounds__(256) void convx(const float* __restrict__ x, short* __restrict__ xb, int n){
  int i = (blockIdx.x*256 + threadIdx.x)*8;
  if (i >= n) return;
  float4 a = *(const float4*)(x+i), b = *(const float4*)(x+i+4);
  bf16x8 o;
  o[0]=f2bf(a.x); o[1]=f2bf(a.y); o[2]=f2bf(a.z); o[3]=f2bf(a.w);
  o[4]=f2bf(b.x); o[5]=f2bf(b.y); o[6]=f2bf(b.z); o[7]=f2bf(b.w);
  *(bf16x8*)(xb+i) = o;
}

// ---- transpose W (K,N) f32 -> Wt (N,K) bf16 ----
__global__ __launch_bounds__(256) void transw(const float* __restrict__ W, short* __restrict__ Wt, int K, int N){
  __shared__ float tl[64][72];
  int tid = threadIdx.x;
  int n0 = blockIdx.x*64, k0 = blockIdx.y*64;
  #pragma unroll
  for (int i=0;i<4;i++){
    int row = (tid>>4) + i*16;
    int col4 = (tid&15)*4;
    float4 v = *(const float4*)&W[(size_t)(k0+row)*N + n0 + col4];
    *(float4*)&tl[row][col4] = v;
  }
  __syncthreads();
  #pragma unroll
  for (int i=0;i<2;i++){
    int nr = (tid>>3) + i*32;
    int ch = tid&7;
    bf16x8 o;
    #pragma unroll
    for (int e=0;e<8;e++) o[e] = f2bf(tl[ch*8+e][nr]);
    *(bf16x8*)&Wt[(size_t)(n0+nr)*K + k0 + ch*8] = o;
  }
}

// ---- GEMM: out(M,N) = A(M,K) @ Bt(N,K)^T + bias.  128x128 tile, 4 waves ----
template<int OUTBF>
__global__ __launch_bounds__(256) void gemm_bt(const short* __restrict__ A, const short* __restrict__ Bt,
           const float* __restrict__ bias, short* __restrict__ outb, float* __restrict__ outf,
           int M, int N, int K)
{
  __shared__ short As[128*32];
  __shared__ short Bs[128*32];
  const int tid = threadIdx.x;
  const int wv = tid >> 6, ln = tid & 63;
  const int lnr = ln & 15, lg = ln >> 4;
  const int m0 = blockIdx.y * 128, n0 = blockIdx.x * 128;
  const int wm = wv >> 1, wn = wv & 1;
  f32x4 acc[4][4];
  #pragma unroll
  for(int i=0;i<4;i++)
    #pragma unroll
    for(int j=0;j<4;j++) acc[i][j] = (f32x4){0.f,0.f,0.f,0.f};

  for (int k0 = 0; k0 < K; k0 += 32){
    #pragma unroll
    for (int c = 0; c < 2; c++){
      int i = c*256 + tid;
      gll16(A  + (size_t)(m0 + (i>>2))*K + k0 + (i&3)*8, (void*)(As + (c*256 + wv*64)*8));
      gll16(Bt + (size_t)(n0 + (i>>2))*K + k0 + (i&3)*8, (void*)(Bs + (c*256 + wv*64)*8));
    }
    __syncthreads();
    bf16x8 af[4], bfr[4];
    #pragma unroll
    for (int mi=0;mi<4;mi++) af[mi]  = *(const bf16x8*)&As[(wm*64 + mi*16 + lnr)*32 + lg*8];
    #pragma unroll
    for (int ni=0;ni<4;ni++) bfr[ni] = *(const bf16x8*)&Bs[(wn*64 + ni*16 + lnr)*32 + lg*8];
    #pragma unroll
    for (int mi=0;mi<4;mi++)
      #pragma unroll
      for (int ni=0;ni<4;ni++)
        acc[mi][ni] = __builtin_amdgcn_mfma_f32_16x16x32_bf16(af[mi], bfr[ni], acc[mi][ni], 0,0,0);
    __syncthreads();
  }

  #pragma unroll
  for (int mi=0;mi<4;mi++){
    #pragma unroll
    for (int ni=0;ni<4;ni++){
      int col = n0 + wn*64 + ni*16 + lnr;
      float bv = bias[col];
      #pragma unroll
      for (int r=0;r<4;r++){
        int row = m0 + wm*64 + mi*16 + lg*4 + r;
        float v = acc[mi][ni][r] + bv;
        if (OUTBF) outb[(size_t)row*N + col] = f2bf(v);
        else       outf[(size_t)row*N + col] = v;
      }
    }
  }
}

// ---- transpose V slice of qkv -> vt (B*H, D, T) bf16 ----
__global__ __launch_bounds__(256) void transv(const short* __restrict__ qkv, short* __restrict__ vt){
  __shared__ short tl[64][72];
  int tid = threadIdx.x;
  int t0 = blockIdx.x*64, bh = blockIdx.y;
  int b = bh>>4, h = bh&15;
  int tr = tid>>2, cc = (tid&3)*16;
  const short* src = &qkv[(size_t)(b*T_ + t0 + tr)*N1_ + 2*C_ + h*D_ + cc];
  #pragma unroll
  for (int i=0;i<4;i++){
    bf16x4 v = *(const bf16x4*)(src + i*4);
    *(bf16x4*)&tl[tr][cc + i*4] = v;
  }
  __syncthreads();
  int d = tid>>2, tc = (tid&3)*16;
  #pragma unroll
  for (int i=0;i<2;i++){
    bf16x8 o;
    #pragma unroll
    for (int e=0;e<8;e++) o[e] = tl[tc + i*8 + e][d];
    *(bf16x8*)&vt[(size_t)(bh*D_ + d)*T_ + t0 + tc + i*8] = o;
  }
}

// ---- flash attention v5: single load round-trip per tile, all-ILP ----
__global__ __launch_bounds__(64) void attn5(const short* __restrict__ qkv, const short* __restrict__ vt,
           const int* __restrict__ mask, short* __restrict__ yb)
{
  const int ln = threadIdx.x & 63;
  const int l31 = ln & 31, hi = ln >> 5;
  const int bh = blockIdx.x, b = bh>>4, hd = bh&15;
  const int s = 63 - (int)blockIdx.y;    // heavy strips dispatch first (LPT)
  const int q0w = s*32;
  const int nt = (s>>1) + 1;
  const float cexp = 0.18033688f;        // 0.125 * log2(e)

  // Q fragments (B-operand): lane holds Q[q0w + l31][ds*16 + hi*8 + e]
  bf16x8 qf[4];
  const short* qbase = qkv + (size_t)(b*T_ + q0w + l31)*N1_ + hd*D_ + hi*8;
  #pragma unroll
  for (int ds=0; ds<4; ds++) qf[ds] = *(const bf16x8*)(qbase + ds*16);

  f32x16 o0, o1;
  #pragma unroll
  for (int r=0;r<16;r++){ o0[r]=0.f; o1[r]=0.f; }
  float mrow = -INFINITY, lsum = 0.f;

  for (int jt = 0; jt < nt; jt++){
    const int j0 = jt << 6;

    // ---- issue ALL independent loads for this tile up front ----
    int mval = mask[b*T_ + j0 + ln];
    const short* kbase = qkv + (size_t)(b*T_ + j0 + l31)*N1_ + C_ + hd*D_ + hi*8;
    bf16x8 kf0[4], kf1[4];
    #pragma unroll
    for (int ds=0; ds<4; ds++){
      kf0[ds] = *(const bf16x8*)(kbase + ds*16);
      kf1[ds] = *(const bf16x8*)(kbase + (size_t)32*N1_ + ds*16);
    }
    const short* vbase = vt + (size_t)(bh*D_ + l31)*T_ + j0 + hi*8;
    bf16x8 vf0[4], vf1[4];
    #pragma unroll
    for (int kt2=0; kt2<2; kt2++){   // V half 0 (keys 0..31 of tile)
      vf0[kt2] = *(const bf16x8*)(vbase + kt2*16);
      vf1[kt2] = *(const bf16x8*)(vbase + (size_t)32*T_ + kt2*16);
    }
    unsigned long long bm = __ballot(mval != 0);

    // ---- QK^T (swapped): waits only on K (counted vmcnt; V stays in flight) ----
    f32x16 s0, s1;
    #pragma unroll
    for (int r=0;r<16;r++){ s0[r]=0.f; s1[r]=0.f; }
    __builtin_amdgcn_s_setprio(1);
    #pragma unroll
    for (int ds=0; ds<4; ds++){
      s0 = __builtin_amdgcn_mfma_f32_32x32x16_bf16(kf0[ds], qf[ds], s0, 0,0,0);
      s1 = __builtin_amdgcn_mfma_f32_32x32x16_bf16(kf1[ds], qf[ds], s1, 0,0,0);
    }
    __builtin_amdgcn_s_setprio(0);

    // V half 1 issues now; latency hides under softmax VALU
    #pragma unroll
    for (int kt2=2; kt2<4; kt2++){
      vf0[kt2] = *(const bf16x8*)(vbase + kt2*16);
      vf1[kt2] = *(const bf16x8*)(vbase + (size_t)32*T_ + kt2*16);
    }

    // ---- masking in raw-s domain ----
    const int qglob = q0w + l31;
    const bool allm = (bm == ~0ull);
    if (!allm){
      #pragma unroll
      for (int r=0;r<16;r++){
        int kr = (r&3) + 8*(r>>2) + 4*hi;
        bool ok0 = (j0 + kr      <= qglob) && ((bm >> kr) & 1);
        bool ok1 = (j0 + kr + 32 <= qglob) && ((bm >> (kr+32)) & 1);
        s0[r] = ok0 ? s0[r] : -INFINITY;
        s1[r] = ok1 ? s1[r] : -INFINITY;
      }
    } else if (j0 + 63 > q0w){   // diagonal tile: causal only
      #pragma unroll
      for (int r=0;r<16;r++){
        int kr = (r&3) + 8*(r>>2) + 4*hi;
        s0[r] = (j0 + kr      <= qglob) ? s0[r] : -INFINITY;
        s1[r] = (j0 + kr + 32 <= qglob) ? s1[r] : -INFINITY;
      }
    }

    // ---- tile max (register tree + one cross-half swap) ----
    float t[8];
    #pragma unroll
    for (int i=0;i<8;i++) t[i] = fmaxf(fmaxf(s0[i], s0[i+8]), fmaxf(s1[i], s1[i+8]));
    #pragma unroll
    for (int i=0;i<4;i++) t[i] = fmaxf(t[i], t[i+4]);
    float pm = fmaxf(fmaxf(t[0],t[1]), fmaxf(t[2],t[3]));
    pm = fmaxf(pm, __shfl_xor(pm, 32));

    // defer-max: rescale only when max grew past threshold
    if (!__all(pm - mrow <= 40.0f)){
      float nm = fmaxf(mrow, pm);
      float alpha = __builtin_amdgcn_exp2f((mrow - nm)*cexp);
      lsum *= alpha;
      mrow = nm;
      #pragma unroll
      for (int r=0;r<16;r++){
        int qsrc = (r&3) + 8*(r>>2) + 4*hi;
        float aO = __shfl(alpha, qsrc);
        o0[r] *= aO; o1[r] *= aO;
      }
    }

    // ---- p = exp2((s-m)*c), in place ----
    #pragma unroll
    for (int r=0;r<16;r++){
      s0[r] = __builtin_amdgcn_exp2f((s0[r]-mrow)*cexp);
      s1[r] = __builtin_amdgcn_exp2f((s1[r]-mrow)*cexp);
    }
    // tile sum
    float u[8];
    #pragma unroll
    for (int i=0;i<8;i++) u[i] = (s0[i]+s0[i+8]) + (s1[i]+s1[i+8]);
    #pragma unroll
    for (int i=0;i<4;i++) u[i] = u[i] + u[i+4];
    float ps = (u[0]+u[1]) + (u[2]+u[3]);
    ps += __shfl_xor(ps, 32);
    lsum += ps;

    // ---- pack P -> bf16 A-fragments (s dies here; no LDS) ----
    unsigned LA[2][4], LB[2][4], SA[2][4], SB[2][4];
    #pragma unroll
    for (int rq=0; rq<4; rq++){
      LA[0][rq] = cvtpk(s0[4*rq],   s0[4*rq+1]);
      LB[0][rq] = cvtpk(s0[4*rq+2], s0[4*rq+3]);
      LA[1][rq] = cvtpk(s1[4*rq],   s1[4*rq+1]);
      LB[1][rq] = cvtpk(s1[4*rq+2], s1[4*rq+3]);
    }
    #pragma unroll
    for (int kt=0; kt<2; kt++)
      #pragma unroll
      for (int rq=0; rq<4; rq++){
        SA[kt][rq] = (unsigned)__shfl_xor((int)LA[kt][rq], 32);
        SB[kt][rq] = (unsigned)__shfl_xor((int)LB[kt][rq], 32);
      }

    // ---- PV over pre-loaded V fragments (no loads inside) ----
    #pragma unroll
    for (int kt2=0; kt2<4; kt2++){
      const int kt = kt2>>1, sub = kt2&1;
      union { unsigned u[4]; bf16x8 v; } pf;
      pf.u[0] = hi ? SA[kt][2*sub+1] : LA[kt][2*sub];
      pf.u[1] = hi ? SB[kt][2*sub+1] : LB[kt][2*sub];
      pf.u[2] = hi ? LA[kt][2*sub+1] : SA[kt][2*sub];
      pf.u[3] = hi ? LB[kt][2*sub+1] : SB[kt][2*sub];
      __builtin_amdgcn_s_setprio(1);
      o0 = __builtin_amdgcn_mfma_f32_32x32x16_bf16(pf.v, vf0[kt2], o0, 0,0,0);
      o1 = __builtin_amdgcn_mfma_f32_32x32x16_bf16(pf.v, vf1[kt2], o1, 0,0,0);
      __builtin_amdgcn_s_setprio(0);
    }
  }

  // epilogue: normalize + store bf16
  float linv = 1.0f / lsum;
  #pragma unroll
  for (int r=0;r<16;r++){
    int qs = (r&3) + 8*(r>>2) + 4*hi;
    float lv = __shfl(linv, qs);
    size_t base = (size_t)(b*T_ + q0w + qs)*C_ + hd*D_ + l31;
    yb[base]      = f2bf(o0[r]*lv);
    yb[base + 32] = f2bf(o1[r]*lv);
  }
}

extern "C" void kernel_launch(void* const* d_in, const int* in_sizes, int n_in,
                              void* d_out, int out_size, void* d_ws, size_t ws_size,
                              hipStream_t stream){
  const float* x     = (const float*)d_in[0];
  const int*   mask  = (const int*)d_in[1];
  const float* Wqkv  = (const float*)d_in[2];
  const float* bqkv  = (const float*)d_in[3];
  const float* Wproj = (const float*)d_in[4];
  const float* bproj = (const float*)d_in[5];
  float* out = (float*)d_out;

  char* w = (char*)d_ws;
  short* xb     = (short*)w; w += (size_t)M_*C_*2;
  short* wqkvT  = (short*)w; w += (size_t)N1_*C_*2;
  short* wprojT = (short*)w; w += (size_t)C_*C_*2;
  short* qkvb   = (short*)w; w += (size_t)M_*N1_*2;
  short* vtb    = (short*)w; w += (size_t)B_*H_*D_*T_*2;
  short* yb     = (short*)w; w += (size_t)M_*C_*2;

  convx<<<dim3((M_*C_)/(256*8)), 256, 0, stream>>>(x, xb, M_*C_);
  transw<<<dim3(N1_/64, C_/64), 256, 0, stream>>>(Wqkv, wqkvT, C_, N1_);
  transw<<<dim3(C_/64,  C_/64), 256, 0, stream>>>(Wproj, wprojT, C_, C_);
  gemm_bt<1><<<dim3(N1_/128, M_/128), 256, 0, stream>>>(xb, wqkvT, bqkv, qkvb, nullptr, M_, N1_, C_);
  transv<<<dim3(T_/64, B_*H_), 256, 0, stream>>>(qkvb, vtb);
  attn5<<<dim3(B_*H_, 64), 64, 0, stream>>>(qkvb, vtb, mask, yb);
  gemm_bt<0><<<dim3(C_/128, M_/128), 256, 0, stream>>>(yb, wprojT, bproj, nullptr, out, M_, C_, C_);
}